// Round 5
// baseline (326.754 us; speedup 1.0000x reference)
//
#include <hip/hip_runtime.h>
#include <cstddef>

// Problem constants (from reference)
constexpr int Bn = 64;     // batch
constexpr int In = 2048;   // input capsules
constexpr int Dk = 8;      // input dim
constexpr int Kc = 16;     // output capsules
constexpr int En = 16;     // output dim
constexpr float EPS = 1e-7f;

// Decomposition
constexpr int NW   = 4;            // waves per block
constexpr int ICW  = 2;            // i's per wave
constexpr int IB   = NW * ICW;     // 8 i's per block
constexpr int P    = In / IB;      // 256 i-chunks
constexpr int BSET = 16;           // batches per block
constexpr int NBG  = Bn / BSET;    // 4 batch groups
constexpr int BLOCKS = P * NBG;    // 1024 blocks = 4/CU, fully resident

// DPP cross-lane add on the VALU pipe (no LDS-pipe traffic).
// ctrl: 0xB1 = quad_perm [1,0,3,2] (xor 1), 0x4E = quad_perm [2,3,0,1] (xor 2),
//       0x124 = row_ror:4, 0x128 = row_ror:8 (16-lane rows)
template<int CTRL>
__device__ __forceinline__ float dpp_add(float v) {
    int r = __builtin_amdgcn_update_dpp(0, __float_as_int(v), CTRL, 0xF, 0xF, true);
    return v + __int_as_float(r);
}

// One routing iteration, atomic-free.
// Block (p,g): 8 i's x 16 batches. Lane l owns (k = l>>2, e4 = (l&3)*4).
// u_hat recomputed from x (LDS broadcast) and W (registers, streamed).
// Softmax over k: e-dot via 2 quad-perm DPP adds; denominator via 2 row_ror
// DPP adds + xor16/xor32 shfls. Cross-wave reduction via a 16 KB LDS slab
// reused in 4 STATICALLY-UNROLLED bl-chunks (runtime chunk index would demote
// acc[] to scratch -- that was Round 4's 2.3x regression).
// UNIFORM=true : c = 1 (1/16 folded into the reduce kernel's scale)
// UNIFORM=false: logits t[k] = dot_e(u_hat[k,:], vsum[b,k,:]); c = softmax_k(t)
template<bool UNIFORM>
__global__ __launch_bounds__(256, 4)
void caps_iter(const float* __restrict__ x,     // [B, I, 8]
               const float* __restrict__ W,     // [I, K, 8, E]
               const float* __restrict__ vsum,  // [B, K, E]
               float* __restrict__ partial)     // [B, P, K*E]
{
    // floats: x-stage [0,1024), vsum [1024,5120), red slab [5120,9216) = 36 KB
    __shared__ __align__(16) float smem[9216];

    const int t  = threadIdx.x;
    const int p  = blockIdx.x >> 2;         // i-chunk
    const int g  = blockIdx.x & 3;          // batch group
    const int b0 = g * BSET;
    const int i0 = p * IB;

    // ---- stage x[b0+bl][i0..i0+7][0..7] -> smem [bl][il][d] (256 float4) ----
    {
        const int bl = t >> 4;              // 0..15
        const int r  = t & 15;              // float4 within the bl row
        ((float4*)smem)[t] = *(const float4*)(x + ((size_t)(b0 + bl) * In + i0) * Dk + (r << 2));
    }
    // ---- stage vsum[b0..b0+15][k][e] -> smem+1024 (1024 float4) ----
    if (!UNIFORM) {
        const float4* vsrc = (const float4*)(vsum + (size_t)b0 * (Kc * En));
        #pragma unroll
        for (int j = 0; j < 4; ++j)
            ((float4*)(smem + 1024))[t + j * 256] = vsrc[t + j * 256];
    }

    const int lane = t & 63;
    const int wv   = t >> 6;
    const int k    = lane >> 2;             // output capsule
    const int e4   = (lane & 3) << 2;       // first of 4 output dims

    __syncthreads();

    float4 acc[BSET];
    #pragma unroll
    for (int bl = 0; bl < BSET; ++bl) acc[bl] = make_float4(0.f, 0.f, 0.f, 0.f);

    #pragma unroll 1
    for (int ii = 0; ii < ICW; ++ii) {
        const int il = wv * ICW + ii;
        const int i  = i0 + il;
        // W[i, k, d, e4:e4+4] staged in registers
        const float* wp = W + (size_t)i * (Kc * Dk * En) + k * (Dk * En) + e4;
        float4 w[8];
        #pragma unroll
        for (int d = 0; d < 8; ++d) w[d] = *(const float4*)(wp + d * En);

        #pragma unroll
        for (int bl = 0; bl < BSET; ++bl) {
            const float* xp = smem + ((bl * IB + il) << 3);   // broadcast reads
            const float4 x0 = *(const float4*)xp;
            const float4 x1 = *(const float4*)(xp + 4);
            const float xs8[8] = {x0.x, x0.y, x0.z, x0.w, x1.x, x1.y, x1.z, x1.w};

            float4 uh = make_float4(0.f, 0.f, 0.f, 0.f);
            #pragma unroll
            for (int d = 0; d < 8; ++d) {
                uh.x = fmaf(xs8[d], w[d].x, uh.x);
                uh.y = fmaf(xs8[d], w[d].y, uh.y);
                uh.z = fmaf(xs8[d], w[d].z, uh.z);
                uh.w = fmaf(xs8[d], w[d].w, uh.w);
            }

            if (UNIFORM) {
                acc[bl].x += uh.x; acc[bl].y += uh.y;
                acc[bl].z += uh.z; acc[bl].w += uh.w;
            } else {
                const float4 vb = *(const float4*)(smem + 1024 + (bl << 8) + k * 16 + e4);
                float tt = uh.x * vb.x + uh.y * vb.y + uh.z * vb.z + uh.w * vb.w;
                tt = dpp_add<0xB1>(tt);           // e-reduce: quad xor 1 (VALU)
                tt = dpp_add<0x4E>(tt);           // e-reduce: quad xor 2 (VALU)
                const float pe = __expf(tt);      // no max-sub: |tt| small
                float den = dpp_add<0x124>(pe);   // k-sum within row: ror 4 (VALU)
                den = dpp_add<0x128>(den);        // k-sum within row: ror 8 (VALU)
                den += __shfl_xor(den, 16);       // cross-row
                den += __shfl_xor(den, 32);
                const float c = pe * __builtin_amdgcn_rcpf(den);
                acc[bl].x = fmaf(c, uh.x, acc[bl].x);
                acc[bl].y = fmaf(c, uh.y, acc[bl].y);
                acc[bl].z = fmaf(c, uh.z, acc[bl].z);
                acc[bl].w = fmaf(c, uh.w, acc[bl].w);
            }
        }
    }

    // ---- cross-wave reduction in 4 STATIC bl-chunks via 16 KB slab ----
    // (fully unrolled: every acc[] index is compile-time constant)
    float* red = smem + 5120;
    #pragma unroll
    for (int c = 0; c < 4; ++c) {
        if (c) __syncthreads();                       // prior chunk's reads done
        float* slab = red + (wv << 10);               // [wv][j][256]
        #pragma unroll
        for (int j = 0; j < 4; ++j)
            *(float4*)(slab + (j << 8) + k * 16 + e4) = acc[c * 4 + j];
        __syncthreads();
        #pragma unroll
        for (int j = 0; j < 4; ++j) {
            const int idx = (j << 8) + t;
            const float sv = red[idx] + red[1024 + idx] + red[2048 + idx] + red[3072 + idx];
            partial[((size_t)(b0 + c * 4 + j) * P + p) * 256 + t] = sv;
        }
    }
}

// Sum the P partials (float4 streams), then v = squash(scale*s) [+ vprev].
// Grid: 64 blocks (one per b), 256 threads = 4 p-groups x 64 element-quads.
__global__ __launch_bounds__(256)
void caps_reduce(const float* __restrict__ partial, float scale,
                 const float* __restrict__ vprev, float* __restrict__ vout)
{
    __shared__ __align__(16) float4 red[4][64];
    const int b  = blockIdx.x;
    const int t  = threadIdx.x;
    const int t4 = t & 63;                  // element-quad index (el = t4*4)
    const int pg = t >> 6;                  // p-group

    const float4* pp = (const float4*)partial + ((size_t)b * P + (pg << 6)) * 64 + t4;
    float4 s0 = make_float4(0.f,0.f,0.f,0.f), s1 = make_float4(0.f,0.f,0.f,0.f);
    #pragma unroll 4
    for (int j = 0; j < 64; j += 2) {
        const float4 a = pp[(size_t)j * 64];
        const float4 c = pp[(size_t)(j + 1) * 64];
        s0.x += a.x; s0.y += a.y; s0.z += a.z; s0.w += a.w;
        s1.x += c.x; s1.y += c.y; s1.z += c.z; s1.w += c.w;
    }
    s0.x += s1.x; s0.y += s1.y; s0.z += s1.z; s0.w += s1.w;
    red[pg][t4] = s0;
    __syncthreads();

    if (t < 64) {
        const float4 a = red[0][t4], c = red[1][t4], d = red[2][t4], e = red[3][t4];
        float4 val;
        val.x = (a.x + c.x + d.x + e.x) * scale;
        val.y = (a.y + c.y + d.y + e.y) * scale;
        val.z = (a.z + c.z + d.z + e.z) * scale;
        val.w = (a.w + c.w + d.w + e.w) * scale;
        // e-norm: t4 = k*4 + eq; quad (bits 0..1) covers the 16 e's
        float sq = val.x*val.x + val.y*val.y + val.z*val.z + val.w*val.w;
        sq += __shfl_xor(sq, 1);
        sq += __shfl_xor(sq, 2);
        const float f = sq / ((1.0f + sq) * sqrtf(sq + EPS));
        float4 v;
        v.x = val.x * f; v.y = val.y * f; v.z = val.z * f; v.w = val.w * f;
        if (vprev) {
            const float4 vp = ((const float4*)vprev)[(b << 6) + t4];
            v.x += vp.x; v.y += vp.y; v.z += vp.z; v.w += vp.w;
        }
        ((float4*)vout)[(b << 6) + t4] = v;
    }
}

extern "C" void kernel_launch(void* const* d_in, const int* in_sizes, int n_in,
                              void* d_out, int out_size, void* d_ws, size_t ws_size,
                              hipStream_t stream) {
    const float* x = (const float*)d_in[0];   // [64, 2048, 8]
    const float* W = (const float*)d_in[1];   // [2048, 16, 8, 16]
    float* out = (float*)d_out;               // [64, 16, 16]
    float* ws  = (float*)d_ws;

    float* v0      = ws;                      // [64,16,16]
    float* vs      = ws + 16384;              // v0 + v1
    float* partial = ws + 32768;              // [64][256][256] = 16.8 MB

    dim3 iblk(256), igrid(BLOCKS);
    dim3 rblk(256), rgrid(Bn);

    // r = 0: uniform coupling (1/16 folded into reduce scale)
    caps_iter<true ><<<igrid, iblk, 0, stream>>>(x, W, nullptr, partial);
    caps_reduce<<<rgrid, rblk, 0, stream>>>(partial, 1.0f / 16.0f, nullptr, v0);

    // r = 1: logits = dot(u_hat, v0);  vs = v0 + v1
    caps_iter<false><<<igrid, iblk, 0, stream>>>(x, W, v0, partial);
    caps_reduce<<<rgrid, rblk, 0, stream>>>(partial, 1.0f, v0, vs);

    // r = 2: logits = dot(u_hat, v0 + v1)
    caps_iter<false><<<igrid, iblk, 0, stream>>>(x, W, vs, partial);
    caps_reduce<<<rgrid, rblk, 0, stream>>>(partial, 1.0f, nullptr, out);
}

// Round 6
// 90.566 us; speedup vs baseline: 3.6079x; 3.6079x over previous
//
#include <hip/hip_runtime.h>
#include <cstddef>

// Problem constants (from reference)
constexpr int Bn = 64;     // batch
constexpr int In = 2048;   // input capsules
constexpr int Dk = 8;      // input dim
constexpr int Kc = 16;     // output capsules
constexpr int En = 16;     // output dim
constexpr float EPS = 1e-7f;

// Decomposition
constexpr int NW   = 4;            // waves per block
constexpr int ICW  = 2;            // i's per wave
constexpr int IB   = NW * ICW;     // 8 i's per block
constexpr int P    = In / IB;      // 256 i-chunks
constexpr int BSET = 16;           // batches per block (2 passes of 8)
constexpr int NBG  = Bn / BSET;    // 4 batch groups
constexpr int BLOCKS = P * NBG;    // 1024 blocks = 4/CU resident

// DPP cross-lane add on the VALU pipe (no LDS-pipe traffic).
// ctrl: 0xB1 = quad_perm [1,0,3,2] (xor 1), 0x4E = quad_perm [2,3,0,1] (xor 2),
//       0x124 = row_ror:4, 0x128 = row_ror:8 (16-lane rows)
template<int CTRL>
__device__ __forceinline__ float dpp_add(float v) {
    int r = __builtin_amdgcn_update_dpp(0, __float_as_int(v), CTRL, 0xF, 0xF, true);
    return v + __int_as_float(r);
}

// One routing iteration, atomic-free.
// Block (p,g): 8 i's x 16 batches, processed as TWO PASSES of 8 batches so the
// live accumulator is only 8 float4 (32 VGPR). Peak live set ~100 VGPR -> no
// launch_bounds cap needed, no spill (R4/R5 lesson: a 128-VGPR cap spilled the
// whole acc[] to scratch -> 300+ MB of HBM scratch traffic).
// Lane l owns (k = l>>2, e4 = (l&3)*4). u_hat recomputed from x (LDS
// broadcast) and W (registers). Softmax over k via DPP adds + 2 shfls.
// Cross-wave reduction through a 16 KB slab in static chunks of 4 batches.
// UNIFORM=true : c = 1 (1/16 folded into the reduce kernel's scale)
// UNIFORM=false: logits t[k] = dot_e(u_hat[k,:], vsum[b,k,:]); c = softmax_k(t)
template<bool UNIFORM>
__global__ __launch_bounds__(256)
void caps_iter(const float* __restrict__ x,     // [B, I, 8]
               const float* __restrict__ W,     // [I, K, 8, E]
               const float* __restrict__ vsum,  // [B, K, E]
               float* __restrict__ partial)     // [B, P, K*E]
{
    // floats: x-stage [0,1024), vsum [1024,5120), red slab [5120,9216) = 36 KB
    __shared__ __align__(16) float smem[9216];

    const int t  = threadIdx.x;
    const int p  = blockIdx.x >> 2;         // i-chunk
    const int g  = blockIdx.x & 3;          // batch group
    const int b0 = g * BSET;
    const int i0 = p * IB;

    // ---- stage x[b0+bl][i0..i0+7][0..7] -> smem [bl][il][d] (256 float4) ----
    {
        const int bl = t >> 4;              // 0..15
        const int r  = t & 15;              // float4 within the bl row
        ((float4*)smem)[t] = *(const float4*)(x + ((size_t)(b0 + bl) * In + i0) * Dk + (r << 2));
    }
    // ---- stage vsum[b0..b0+15][k][e] -> smem+1024 (1024 float4) ----
    if (!UNIFORM) {
        const float4* vsrc = (const float4*)(vsum + (size_t)b0 * (Kc * En));
        #pragma unroll
        for (int j = 0; j < 4; ++j)
            ((float4*)(smem + 1024))[t + j * 256] = vsrc[t + j * 256];
    }

    const int lane = t & 63;
    const int wv   = t >> 6;
    const int k    = lane >> 2;             // output capsule
    const int e4   = (lane & 3) << 2;       // first of 4 output dims

    __syncthreads();

    float* red = smem + 5120;

    #pragma unroll
    for (int h = 0; h < 2; ++h) {           // batch half: bl = h*8 .. h*8+7
        float4 acc[8];
        #pragma unroll
        for (int j = 0; j < 8; ++j) acc[j] = make_float4(0.f, 0.f, 0.f, 0.f);

        #pragma unroll
        for (int ii = 0; ii < ICW; ++ii) {
            const int il = wv * ICW + ii;
            const int i  = i0 + il;
            // W[i, k, d, e4:e4+4] staged in registers (L1-hot on second half)
            const float* wp = W + (size_t)i * (Kc * Dk * En) + k * (Dk * En) + e4;
            float4 w[8];
            #pragma unroll
            for (int d = 0; d < 8; ++d) w[d] = *(const float4*)(wp + d * En);

            #pragma unroll
            for (int b8 = 0; b8 < 8; ++b8) {
                const int bl = h * 8 + b8;
                const float* xp = smem + ((bl * IB + il) << 3);   // broadcast
                const float4 x0 = *(const float4*)xp;
                const float4 x1 = *(const float4*)(xp + 4);
                const float xs8[8] = {x0.x, x0.y, x0.z, x0.w, x1.x, x1.y, x1.z, x1.w};

                float4 uh = make_float4(0.f, 0.f, 0.f, 0.f);
                #pragma unroll
                for (int d = 0; d < 8; ++d) {
                    uh.x = fmaf(xs8[d], w[d].x, uh.x);
                    uh.y = fmaf(xs8[d], w[d].y, uh.y);
                    uh.z = fmaf(xs8[d], w[d].z, uh.z);
                    uh.w = fmaf(xs8[d], w[d].w, uh.w);
                }

                if (UNIFORM) {
                    acc[b8].x += uh.x; acc[b8].y += uh.y;
                    acc[b8].z += uh.z; acc[b8].w += uh.w;
                } else {
                    const float4 vb = *(const float4*)(smem + 1024 + (bl << 8) + k * 16 + e4);
                    float tt = uh.x * vb.x + uh.y * vb.y + uh.z * vb.z + uh.w * vb.w;
                    tt = dpp_add<0xB1>(tt);           // e-reduce: quad xor 1
                    tt = dpp_add<0x4E>(tt);           // e-reduce: quad xor 2
                    const float pe = __expf(tt);      // no max-sub: |tt| small
                    float den = dpp_add<0x124>(pe);   // k-sum in row: ror 4
                    den = dpp_add<0x128>(den);        // k-sum in row: ror 8
                    den += __shfl_xor(den, 16);       // cross-row
                    den += __shfl_xor(den, 32);
                    const float c = pe * __builtin_amdgcn_rcpf(den);
                    acc[b8].x = fmaf(c, uh.x, acc[b8].x);
                    acc[b8].y = fmaf(c, uh.y, acc[b8].y);
                    acc[b8].z = fmaf(c, uh.z, acc[b8].z);
                    acc[b8].w = fmaf(c, uh.w, acc[b8].w);
                }
            }
        }

        // ---- this half's cross-wave reduction: 2 static chunks of 4 bl ----
        #pragma unroll
        for (int c = 0; c < 2; ++c) {
            __syncthreads();                          // slab safe to overwrite
            float* slab = red + (wv << 10);           // [wv][j][256]
            #pragma unroll
            for (int j = 0; j < 4; ++j)
                *(float4*)(slab + (j << 8) + k * 16 + e4) = acc[c * 4 + j];
            __syncthreads();
            #pragma unroll
            for (int j = 0; j < 4; ++j) {
                const int idx = (j << 8) + t;
                const float sv = red[idx] + red[1024 + idx] + red[2048 + idx] + red[3072 + idx];
                partial[((size_t)(b0 + h * 8 + c * 4 + j) * P + p) * 256 + t] = sv;
            }
        }
    }
}

// Sum the P partials (float4 streams), then v = squash(scale*s) [+ vprev].
// Grid: 64 blocks (one per b), 256 threads = 4 p-groups x 64 element-quads.
__global__ __launch_bounds__(256)
void caps_reduce(const float* __restrict__ partial, float scale,
                 const float* __restrict__ vprev, float* __restrict__ vout)
{
    __shared__ __align__(16) float4 red[4][64];
    const int b  = blockIdx.x;
    const int t  = threadIdx.x;
    const int t4 = t & 63;                  // element-quad index (el = t4*4)
    const int pg = t >> 6;                  // p-group

    const float4* pp = (const float4*)partial + ((size_t)b * P + (pg << 6)) * 64 + t4;
    float4 s0 = make_float4(0.f,0.f,0.f,0.f), s1 = make_float4(0.f,0.f,0.f,0.f);
    #pragma unroll 4
    for (int j = 0; j < 64; j += 2) {
        const float4 a = pp[(size_t)j * 64];
        const float4 c = pp[(size_t)(j + 1) * 64];
        s0.x += a.x; s0.y += a.y; s0.z += a.z; s0.w += a.w;
        s1.x += c.x; s1.y += c.y; s1.z += c.z; s1.w += c.w;
    }
    s0.x += s1.x; s0.y += s1.y; s0.z += s1.z; s0.w += s1.w;
    red[pg][t4] = s0;
    __syncthreads();

    if (t < 64) {
        const float4 a = red[0][t4], c = red[1][t4], d = red[2][t4], e = red[3][t4];
        float4 val;
        val.x = (a.x + c.x + d.x + e.x) * scale;
        val.y = (a.y + c.y + d.y + e.y) * scale;
        val.z = (a.z + c.z + d.z + e.z) * scale;
        val.w = (a.w + c.w + d.w + e.w) * scale;
        // e-norm: t4 = k*4 + eq; quad (bits 0..1) covers the 16 e's
        float sq = val.x*val.x + val.y*val.y + val.z*val.z + val.w*val.w;
        sq += __shfl_xor(sq, 1);
        sq += __shfl_xor(sq, 2);
        const float f = sq / ((1.0f + sq) * sqrtf(sq + EPS));
        float4 v;
        v.x = val.x * f; v.y = val.y * f; v.z = val.z * f; v.w = val.w * f;
        if (vprev) {
            const float4 vp = ((const float4*)vprev)[(b << 6) + t4];
            v.x += vp.x; v.y += vp.y; v.z += vp.z; v.w += vp.w;
        }
        ((float4*)vout)[(b << 6) + t4] = v;
    }
}

extern "C" void kernel_launch(void* const* d_in, const int* in_sizes, int n_in,
                              void* d_out, int out_size, void* d_ws, size_t ws_size,
                              hipStream_t stream) {
    const float* x = (const float*)d_in[0];   // [64, 2048, 8]
    const float* W = (const float*)d_in[1];   // [2048, 16, 8, 16]
    float* out = (float*)d_out;               // [64, 16, 16]
    float* ws  = (float*)d_ws;

    float* v0      = ws;                      // [64,16,16]
    float* vs      = ws + 16384;              // v0 + v1
    float* partial = ws + 32768;              // [64][256][256] = 16.8 MB

    dim3 iblk(256), igrid(BLOCKS);
    dim3 rblk(256), rgrid(Bn);

    // r = 0: uniform coupling (1/16 folded into reduce scale)
    caps_iter<true ><<<igrid, iblk, 0, stream>>>(x, W, nullptr, partial);
    caps_reduce<<<rgrid, rblk, 0, stream>>>(partial, 1.0f / 16.0f, nullptr, v0);

    // r = 1: logits = dot(u_hat, v0);  vs = v0 + v1
    caps_iter<false><<<igrid, iblk, 0, stream>>>(x, W, v0, partial);
    caps_reduce<<<rgrid, rblk, 0, stream>>>(partial, 1.0f, v0, vs);

    // r = 2: logits = dot(u_hat, v0 + v1)
    caps_iter<false><<<igrid, iblk, 0, stream>>>(x, W, vs, partial);
    caps_reduce<<<rgrid, rblk, 0, stream>>>(partial, 1.0f, nullptr, out);
}

// Round 8
// 64.072 us; speedup vs baseline: 5.0998x; 1.4135x over previous
//
#include <hip/hip_runtime.h>
#include <hip/hip_cooperative_groups.h>
#include <cstddef>

namespace cg = cooperative_groups;

// Problem constants (from reference)
constexpr int Bn = 64;     // batch
constexpr int In = 2048;   // input capsules
constexpr int Dk = 8;      // input dim
constexpr int Kc = 16;     // output capsules
constexpr int En = 16;     // output dim
constexpr float EPS = 1e-7f;

// Decomposition: block = (p, g) tile of 8 i's x 16 batches; wave owns 4
// batches x all 8 i's -> disjoint outputs per wave -> NO cross-wave slab.
constexpr int IB   = 8;            // i's per block
constexpr int P    = In / IB;      // 256 i-chunks
constexpr int BSET = 16;           // batches per block (4 per wave)
constexpr int NBG  = Bn / BSET;    // 4 batch groups
constexpr int BLOCKS = P * NBG;    // 1024
constexpr int NXCD = 8;
constexpr int PPX  = P / NXCD;     // 32 p-chunks per XCD (2 MB of W < 4 MB L2)

// DPP cross-lane add on the VALU pipe (no LDS-pipe traffic).
// ctrl: 0xB1 = quad_perm [1,0,3,2] (xor 1), 0x4E = quad_perm [2,3,0,1] (xor 2),
//       0x124 = row_ror:4, 0x128 = row_ror:8 (16-lane rows)
template<int CTRL>
__device__ __forceinline__ float dpp_add(float v) {
    int r = __builtin_amdgcn_update_dpp(0, __float_as_int(v), CTRL, 0xF, 0xF, true);
    return v + __int_as_float(r);
}

// One routing iteration for a (p, g) tile. x tile already staged in
// smemx[0,1024) as [bl][il][d]. Wave wv handles batches bw..bw+3 (bw = b0+wv*4)
// across all 8 i's; acc[4] = 16 VGPR (no spill; R4/R5 lesson: keep live set
// small STRUCTURALLY, never via launch_bounds caps). vsum slice lives in 4
// registers per lane, loaded from the 16 KB L2-resident v-buffer.
// Barrier-free; one plain float4 store per (batch, lane) at the end.
template<bool UNIFORM>
__device__ __forceinline__ void iter_body(const float* __restrict__ smemx,
        const float* __restrict__ W, const float* __restrict__ vsg,
        float* __restrict__ partial, int p, int b0, int i0, int t)
{
    const int lane = t & 63;
    const int wv   = t >> 6;
    const int k    = lane >> 2;             // output capsule
    const int e4   = (lane & 3) << 2;       // first of 4 output dims
    const int bw   = b0 + (wv << 2);        // this wave's first batch

    float4 vb[4];
    if (!UNIFORM) {
        #pragma unroll
        for (int b4 = 0; b4 < 4; ++b4)
            vb[b4] = *(const float4*)(vsg + ((bw + b4) << 8) + k * 16 + e4);
    }

    float4 acc[4];
    #pragma unroll
    for (int b4 = 0; b4 < 4; ++b4) acc[b4] = make_float4(0.f, 0.f, 0.f, 0.f);

    #pragma unroll 1
    for (int ii = 0; ii < IB; ++ii) {
        const int i = i0 + ii;
        const float* wp = W + (size_t)i * (Kc * Dk * En) + k * (Dk * En) + e4;
        float4 w[8];
        #pragma unroll
        for (int d = 0; d < 8; ++d) w[d] = *(const float4*)(wp + d * En);

        #pragma unroll
        for (int b4 = 0; b4 < 4; ++b4) {
            const int bl = (wv << 2) + b4;
            const float* xp = smemx + (((bl << 3) + ii) << 3);  // [bl][ii][*]
            const float4 x0 = *(const float4*)xp;
            const float4 x1 = *(const float4*)(xp + 4);
            const float xs8[8] = {x0.x, x0.y, x0.z, x0.w, x1.x, x1.y, x1.z, x1.w};

            float4 uh = make_float4(0.f, 0.f, 0.f, 0.f);
            #pragma unroll
            for (int d = 0; d < 8; ++d) {
                uh.x = fmaf(xs8[d], w[d].x, uh.x);
                uh.y = fmaf(xs8[d], w[d].y, uh.y);
                uh.z = fmaf(xs8[d], w[d].z, uh.z);
                uh.w = fmaf(xs8[d], w[d].w, uh.w);
            }

            if (UNIFORM) {
                acc[b4].x += uh.x; acc[b4].y += uh.y;
                acc[b4].z += uh.z; acc[b4].w += uh.w;
            } else {
                float tt = uh.x * vb[b4].x + uh.y * vb[b4].y
                         + uh.z * vb[b4].z + uh.w * vb[b4].w;
                tt = dpp_add<0xB1>(tt);           // e-reduce: quad xor 1
                tt = dpp_add<0x4E>(tt);           // e-reduce: quad xor 2
                const float pe = __expf(tt);      // no max-sub: |tt| small
                float den = dpp_add<0x124>(pe);   // k-sum in row: ror 4
                den = dpp_add<0x128>(den);        // k-sum in row: ror 8
                den += __shfl_xor(den, 16);       // cross-row
                den += __shfl_xor(den, 32);
                const float c = pe * __builtin_amdgcn_rcpf(den);
                acc[b4].x = fmaf(c, uh.x, acc[b4].x);
                acc[b4].y = fmaf(c, uh.y, acc[b4].y);
                acc[b4].z = fmaf(c, uh.z, acc[b4].z);
                acc[b4].w = fmaf(c, uh.w, acc[b4].w);
            }
        }
    }

    #pragma unroll
    for (int b4 = 0; b4 < 4; ++b4)
        *(float4*)(partial + ((size_t)(bw + b4) * P + p) * 256 + k * 16 + e4) = acc[b4];
}

// Sum the P=256 partials, squash, optional vprev add. rb = 0..255:
// b = rb>>2, element-quarter q = rb&3. 4 p-groups of 64 p's per thread-group,
// combined via smem[1024,1280).
__device__ __forceinline__ void reduce_phase(float* smem,
        const float* __restrict__ partial, float scale,
        const float* __restrict__ vprev, float* __restrict__ vout, int rb, int t)
{
    const int b  = rb >> 2;
    const int q  = rb & 3;
    const int t4 = t & 63;
    const int pg = t >> 6;
    const int el = (q << 6) + t4;           // element 0..255 (= k*16+e)
    const float* pp = partial + (size_t)b * (P * 256) + ((pg << 6) * 256) + el;

    float s0 = 0.f, s1 = 0.f, s2 = 0.f, s3 = 0.f;
    #pragma unroll 4
    for (int j = 0; j < 64; j += 4) {
        s0 += pp[(j + 0) * 256];
        s1 += pp[(j + 1) * 256];
        s2 += pp[(j + 2) * 256];
        s3 += pp[(j + 3) * 256];
    }
    float* red = smem + 1024;
    red[(pg << 6) + t4] = (s0 + s1) + (s2 + s3);
    __syncthreads();

    if (t < 64) {
        const float val = (red[t4] + red[64 + t4] + red[128 + t4] + red[192 + t4]) * scale;
        float sq = val * val;                // e = el & 15 = t4 & 15
        sq += __shfl_xor(sq, 1);
        sq += __shfl_xor(sq, 2);
        sq += __shfl_xor(sq, 4);
        sq += __shfl_xor(sq, 8);
        const float f = sq / ((1.0f + sq) * sqrtf(sq + EPS));
        float v = val * f;
        if (vprev) v += vprev[(b << 8) + el];
        vout[(b << 8) + el] = v;
    }
    __syncthreads();
}

// XCD-bijective tile mapping: physical XCD = bid&7 (round-robin dispatch);
// each XCD owns a contiguous 32-chunk p-range (2 MB of W -> L2-resident) and
// all 4 batch-group duplicates of a p run on the same XCD.
__device__ __forceinline__ void tile_map(int bid, int& p, int& b0, int& i0) {
    const int xcd = bid & 7;
    const int j   = bid >> 3;
    p  = xcd * PPX + (j & (PPX - 1));
    b0 = (j >> 5) * BSET;
    i0 = p * IB;
}

__device__ __forceinline__ void stage_x(float* smem, const float* __restrict__ x,
                                        int b0, int i0, int t) {
    const int bl = t >> 4;
    const int r  = t & 15;
    ((float4*)smem)[t] = *(const float4*)(x + ((size_t)(b0 + bl) * In + i0) * Dk + (r << 2));
}

// ---------------- fused cooperative kernel (8 KB LDS) ----------------
__global__ __launch_bounds__(256)
void caps_fused(const float* __restrict__ x, const float* __restrict__ W,
                float* __restrict__ partial, float* __restrict__ v0,
                float* __restrict__ vs, float* __restrict__ out)
{
    cg::grid_group grid = cg::this_grid();
    __shared__ __align__(16) float smem[2048];   // x [0,1024) | red [1024,1280)

    const int t = threadIdx.x, bid = blockIdx.x;
    int p, b0, i0;
    tile_map(bid, p, b0, i0);

    stage_x(smem, x, b0, i0, t);        // once, reused by all 3 iterations
    __syncthreads();

    // r = 0: uniform coupling (1/16 folded into reduce scale)
    iter_body<true>(smem, W, nullptr, partial, p, b0, i0, t);
    grid.sync();
    if (bid < 256) reduce_phase(smem, partial, 1.0f / 16.0f, nullptr, v0, bid, t);
    grid.sync();

    // r = 1: logits = dot(u_hat, v0);  vs = v0 + v1
    iter_body<false>(smem, W, v0, partial, p, b0, i0, t);
    grid.sync();
    if (bid < 256) reduce_phase(smem, partial, 1.0f, v0, vs, bid, t);
    grid.sync();

    // r = 2: logits = dot(u_hat, v0 + v1); final squash -> out
    iter_body<false>(smem, W, vs, partial, p, b0, i0, t);
    grid.sync();
    if (bid < 256) reduce_phase(smem, partial, 1.0f, nullptr, out, bid, t);
}

// ---------------- fallback: same phases as separate kernels ----------------
template<bool UNIFORM>
__global__ __launch_bounds__(256)
void caps_iter_g(const float* __restrict__ x, const float* __restrict__ W,
                 const float* __restrict__ vsg, float* __restrict__ partial)
{
    __shared__ __align__(16) float smem[2048];
    const int t = threadIdx.x;
    int p, b0, i0;
    tile_map(blockIdx.x, p, b0, i0);
    stage_x(smem, x, b0, i0, t);
    __syncthreads();
    iter_body<UNIFORM>(smem, W, vsg, partial, p, b0, i0, t);
}

__global__ __launch_bounds__(256)
void caps_reduce_g(const float* __restrict__ partial, float scale,
                   const float* __restrict__ vprev, float* __restrict__ vout)
{
    __shared__ __align__(16) float smem[2048];
    reduce_phase(smem, partial, scale, vprev, vout, blockIdx.x, threadIdx.x);
}

extern "C" void kernel_launch(void* const* d_in, const int* in_sizes, int n_in,
                              void* d_out, int out_size, void* d_ws, size_t ws_size,
                              hipStream_t stream) {
    const float* x = (const float*)d_in[0];   // [64, 2048, 8]
    const float* W = (const float*)d_in[1];   // [2048, 16, 8, 16]
    float* out = (float*)d_out;               // [64, 16, 16]
    float* ws  = (float*)d_ws;

    float* v0      = ws;                      // [64,16,16]
    float* vs      = ws + 16384;              // v0 + v1
    float* partial = ws + 32768;              // [64][256][256] = 16.8 MB

    // Host-side co-residency gate (capture-safe: no stream ops). Only launch
    // cooperatively if the runtime agrees all 1024 blocks fit.
    int dev = 0;
    hipGetDevice(&dev);
    int numCU = 0;
    hipDeviceGetAttribute(&numCU, hipDeviceAttributeMultiprocessorCount, dev);
    int maxB = 0;
    hipError_t oe = hipOccupancyMaxActiveBlocksPerMultiprocessor(
        &maxB, (const void*)caps_fused, 256, 0);
    const bool coop = (oe == hipSuccess) && numCU > 0 &&
                      ((long)maxB * numCU >= BLOCKS);

    if (coop) {
        void* args[] = { (void*)&x, (void*)&W, (void*)&partial,
                         (void*)&v0, (void*)&vs, (void*)&out };
        hipLaunchCooperativeKernel((void*)caps_fused, dim3(BLOCKS), dim3(256),
                                   args, 0, stream);
    } else {
        caps_iter_g<true ><<<BLOCKS, 256, 0, stream>>>(x, W, nullptr, partial);
        caps_reduce_g<<<256, 256, 0, stream>>>(partial, 1.0f / 16.0f, nullptr, v0);
        caps_iter_g<false><<<BLOCKS, 256, 0, stream>>>(x, W, v0, partial);
        caps_reduce_g<<<256, 256, 0, stream>>>(partial, 1.0f, v0, vs);
        caps_iter_g<false><<<BLOCKS, 256, 0, stream>>>(x, W, vs, partial);
        caps_reduce_g<<<256, 256, 0, stream>>>(partial, 1.0f, nullptr, out);
    }
}